// Round 1
// baseline (621.758 us; speedup 1.0000x reference)
//
#include <hip/hip_runtime.h>

// B=4, M=4096, N2=8192 (k/v split at 4096), D=HID=128, all f32 in/out.
// out = softmax(q k^T /sqrt(128)) v + mask v
//     = rl * (e^t @ V) + mask @ V        (fixed-max softmax; rl = 1/rowsum(e^t))
//
// ws layout (bf16): q[4][4096][128] | k[4][4096][128] | vT[4][128][4096]  = 12 MB

typedef __attribute__((ext_vector_type(8))) short bf16x8;
typedef __attribute__((ext_vector_type(4))) float f32x4;

static constexpr float kScale = 0.08838834764831845f;   // 1/sqrt(128)
static constexpr float kLog2e = 1.4426950408889634f;

__device__ __forceinline__ unsigned short f2bf(float f) {
  unsigned int u = __float_as_uint(f);
  u = (u + 0x7fffu + ((u >> 16) & 1u)) >> 16;   // RNE
  return (unsigned short)u;
}

__device__ __forceinline__ float fast_exp2(float v) {
#if __has_builtin(__builtin_amdgcn_exp2f)
  return __builtin_amdgcn_exp2f(v);
#else
  return exp2f(v);
#endif
}

// ---------------- kernel 1: projections -------------------------------------
// bid <  256 : q rows  (x @ Wq^T)    -> qws row-major bf16
// bid >= 256 : kv rows (cond @ Wkv^T): n2<4096 -> kws row-major, else vT scatter
__global__ __launch_bounds__(256) void proj_kernel(
    const float* __restrict__ x, const float* __restrict__ cond,
    const float* __restrict__ Wq, const float* __restrict__ Wkv,
    unsigned short* __restrict__ qws, unsigned short* __restrict__ kws,
    unsigned short* __restrict__ vTws)
{
  __shared__ __align__(16) unsigned short ldsT[128][88];  // 88: 16B-aligned rows, ~2-way banks
  const int bid = blockIdx.x;
  const int tid = threadIdx.x;
  const int wave = tid >> 6;
  const int l = tid & 63;
  const int l15 = l & 15, l4 = l >> 4;

  const float* src; const float* W;
  int mode; size_t row0;
  if (bid < 256) { mode = 0; src = x; W = Wq; row0 = (size_t)bid * 64; }
  else {
    row0 = (size_t)(bid - 256) * 64;
    src = cond; W = Wkv;
    mode = ((int)(row0 & 8191) < 4096) ? 1 : 2;
  }
  const size_t rw = row0 + wave * 16;

  // A-frags: 16 input rows, f32 -> bf16
  bf16x8 af[4];
  {
    const float* rp = src + (rw + l15) * 128 + l4 * 8;
    #pragma unroll
    for (int ks = 0; ks < 4; ks++) {
      float t[8];
      *(float4*)&t[0] = *(const float4*)(rp + ks * 32);
      *(float4*)&t[4] = *(const float4*)(rp + ks * 32 + 4);
      bf16x8 a;
      #pragma unroll
      for (int j = 0; j < 8; j++) a[j] = (short)f2bf(t[j]);
      af[ks] = a;
    }
  }

  f32x4 acc[8];
  #pragma unroll
  for (int d = 0; d < 8; d++) acc[d] = (f32x4){0.f, 0.f, 0.f, 0.f};

  #pragma unroll
  for (int d = 0; d < 8; d++) {
    const float* wp = W + (d * 16 + l15) * 128 + l4 * 8;   // B[k=i][col=d] = W[d][i]
    #pragma unroll
    for (int ks = 0; ks < 4; ks++) {
      float t[8];
      *(float4*)&t[0] = *(const float4*)(wp + ks * 32);
      *(float4*)&t[4] = *(const float4*)(wp + ks * 32 + 4);
      bf16x8 wf;
      #pragma unroll
      for (int j = 0; j < 8; j++) wf[j] = (short)f2bf(t[j]);
      acc[d] = __builtin_amdgcn_mfma_f32_16x16x32_bf16(af[ks], wf, acc[d], 0, 0, 0);
    }
  }

  if (mode < 2) {
    size_t obase; unsigned short* outp;
    if (mode == 0) { outp = qws; obase = rw; }                  // flat b*4096+m
    else { outp = kws; obase = (rw >> 13) * 4096 + (rw & 8191); }
    #pragma unroll
    for (int d = 0; d < 8; d++)
      #pragma unroll
      for (int r = 0; r < 4; r++)
        outp[(obase + l4 * 4 + r) * 128 + d * 16 + l15] = f2bf(acc[d][r]);
  } else {
    // transpose 64 v-rows through LDS -> vT[b][d][n]
    #pragma unroll
    for (int d = 0; d < 8; d++)
      #pragma unroll
      for (int r = 0; r < 4; r++)
        ldsT[d * 16 + l15][wave * 16 + l4 * 4 + r] = f2bf(acc[d][r]);
    __syncthreads();
    const size_t b = row0 >> 13;
    const int n0 = (int)(row0 & 8191) - 4096;
    const int dd = tid >> 1, half = tid & 1;
    const unsigned short* sp = &ldsT[dd][half * 32];
    unsigned short* gp = vTws + ((size_t)b * 128 + dd) * 4096 + n0 + half * 32;
    #pragma unroll
    for (int i = 0; i < 4; i++)
      *(int4*)(gp + i * 8) = *(const int4*)(sp + i * 8);
  }
}

// ---------------- kernel 2: fused attention ---------------------------------
// 256 blocks (1/CU), 512 thr = 8 waves: wave = (rowgrp 0..3) x (n-half 0..1).
// Each wave: 16 q-rows, n in [nh*2048, nh*2048+2048) in 64-wide tiles.
__global__ __launch_bounds__(512) void attn_kernel(
    const unsigned short* __restrict__ qws,
    const unsigned short* __restrict__ kws,
    const unsigned short* __restrict__ vTws,
    const float* __restrict__ mask,
    float* __restrict__ out)
{
  __shared__ __align__(16) unsigned short pbuf[2][8][16][72]; // [P1|P2][wave][row][col]
  __shared__ float stats[2][64];                              // [n-half][row] row-sums

  const int bid = blockIdx.x;
  // XCD swizzle: pin batch b to XCD pair {2b,2b+1} so k+vT (2MB) stay L2-resident.
  const int xcd = bid & 7, grp = bid >> 3;
  const int b = xcd >> 1;
  const int m0 = (grp * 2 + (xcd & 1)) * 64;

  const int tid = threadIdx.x;
  const int w = tid >> 6, l = tid & 63;
  const int rg = w & 3, nh = w >> 2;
  const int l15 = l & 15, l4 = l >> 4;

  // hoist q A-frags (row = l&15, k = (l>>4)*8+j)
  bf16x8 qf[4];
  {
    const unsigned short* qp = qws + ((size_t)b * 4096 + m0 + rg * 16 + l15) * 128 + l4 * 8;
    #pragma unroll
    for (int ks = 0; ks < 4; ks++) qf[ks] = *(const bf16x8*)(qp + ks * 32);
  }

  f32x4 acc1[8], acc2[8];
  #pragma unroll
  for (int d = 0; d < 8; d++) { acc1[d] = (f32x4){0,0,0,0}; acc2[d] = (f32x4){0,0,0,0}; }
  float lsum[4] = {0.f, 0.f, 0.f, 0.f};

  const unsigned short* kbase = kws  + (size_t)b * 4096 * 128;
  const unsigned short* vbase = vTws + (size_t)b * 128 * 4096;
  const float* mbase = mask + ((size_t)b * 4096 + m0 + rg * 16) * 4096;

  for (int nt = 0; nt < 32; nt++) {
    const int n0 = nh * 2048 + nt * 64;

    // S = q k^T  (D-layout: row=(l>>4)*4+r, col=ns*16+(l&15))
    f32x4 sacc[4];
    #pragma unroll
    for (int ns = 0; ns < 4; ns++) {
      sacc[ns] = (f32x4){0,0,0,0};
      const unsigned short* kp = kbase + (size_t)(n0 + ns * 16 + l15) * 128 + l4 * 8;
      #pragma unroll
      for (int ks = 0; ks < 4; ks++) {
        bf16x8 kf = *(const bf16x8*)(kp + ks * 32);
        sacc[ns] = __builtin_amdgcn_mfma_f32_16x16x32_bf16(qf[ks], kf, sacc[ns], 0, 0, 0);
      }
    }

    // P1 = bf16(e^t), accumulate row-sums (per-lane partial; reduced at end)
    #pragma unroll
    for (int ns = 0; ns < 4; ns++) {
      #pragma unroll
      for (int r = 0; r < 4; r++) {
        float e = fast_exp2(sacc[ns][r] * (kScale * kLog2e));
        lsum[r] += e;
        pbuf[0][w][l4 * 4 + r][ns * 16 + l15] = f2bf(e);
      }
    }

    // P2 = bf16(mask tile), loaded coalesced (256B per row)
    #pragma unroll
    for (int i = 0; i < 4; i++) {
      const int r = i * 4 + l4, c = l15 * 4;
      float4 mv = *(const float4*)(mbase + (size_t)r * 4096 + n0 + c);
      ushort4 mm = make_ushort4(f2bf(mv.x), f2bf(mv.y), f2bf(mv.z), f2bf(mv.w));
      *(ushort4*)&pbuf[1][w][r][c] = mm;
    }

    // PV: A-frags (row=l&15, k=(l>>4)*8+j) from LDS; shared V B-frags from vT
    bf16x8 a1[2], a2[2];
    #pragma unroll
    for (int ks = 0; ks < 2; ks++) {
      a1[ks] = *(const bf16x8*)&pbuf[0][w][l15][ks * 32 + l4 * 8];
      a2[ks] = *(const bf16x8*)&pbuf[1][w][l15][ks * 32 + l4 * 8];
    }
    #pragma unroll
    for (int d = 0; d < 8; d++) {
      const unsigned short* vp = vbase + (size_t)(d * 16 + l15) * 4096 + n0 + l4 * 8;
      #pragma unroll
      for (int ks = 0; ks < 2; ks++) {
        bf16x8 vf = *(const bf16x8*)(vp + ks * 32);
        acc1[d] = __builtin_amdgcn_mfma_f32_16x16x32_bf16(a1[ks], vf, acc1[d], 0, 0, 0);
        acc2[d] = __builtin_amdgcn_mfma_f32_16x16x32_bf16(a2[ks], vf, acc2[d], 0, 0, 0);
      }
    }
  }

  // finalize row-sums: reduce over 16 lanes, combine the two n-halves via LDS
  #pragma unroll
  for (int r = 0; r < 4; r++) {
    float s = lsum[r];
    s += __shfl_xor(s, 1); s += __shfl_xor(s, 2);
    s += __shfl_xor(s, 4); s += __shfl_xor(s, 8);
    lsum[r] = s;
  }
  if (l15 == 0) {
    #pragma unroll
    for (int r = 0; r < 4; r++) stats[nh][rg * 16 + l4 * 4 + r] = lsum[r];
  }
  __syncthreads();

  float rl[4];
  #pragma unroll
  for (int r = 0; r < 4; r++) {
    const int row = rg * 16 + l4 * 4 + r;
    rl[r] = 1.0f / (stats[0][row] + stats[1][row]);
  }

  // combine the two n-half partial outputs (cb aliases pbuf; all reads done)
  float* cb = (float*)pbuf;   // needs 32KB <= 36.9KB
  if (nh == 1) {
    #pragma unroll
    for (int d = 0; d < 8; d++)
      #pragma unroll
      for (int r = 0; r < 4; r++)
        cb[(rg * 16 + l4 * 4 + r) * 128 + d * 16 + l15] = acc1[d][r] * rl[r] + acc2[d][r];
  }
  __syncthreads();
  if (nh == 0) {
    float* op = out + ((size_t)b * 4096 + m0) * 128;
    #pragma unroll
    for (int d = 0; d < 8; d++)
      #pragma unroll
      for (int r = 0; r < 4; r++) {
        const int row = rg * 16 + l4 * 4 + r;
        op[(size_t)row * 128 + d * 16 + l15] =
            acc1[d][r] * rl[r] + acc2[d][r] + cb[row * 128 + d * 16 + l15];
      }
  }
}

extern "C" void kernel_launch(void* const* d_in, const int* in_sizes, int n_in,
                              void* d_out, int out_size, void* d_ws, size_t ws_size,
                              hipStream_t stream) {
  const float* x    = (const float*)d_in[0];
  const float* cond = (const float*)d_in[1];
  const float* mask = (const float*)d_in[2];
  const float* Wq   = (const float*)d_in[3];
  const float* Wkv  = (const float*)d_in[4];

  unsigned short* qws = (unsigned short*)d_ws;
  unsigned short* kws = qws + (size_t)4 * 4096 * 128;
  unsigned short* vT  = kws + (size_t)4 * 4096 * 128;

  hipLaunchKernelGGL(proj_kernel, dim3(768), dim3(256), 0, stream,
                     x, cond, Wq, Wkv, qws, kws, vT);
  hipLaunchKernelGGL(attn_kernel, dim3(256), dim3(512), 0, stream,
                     qws, kws, vT, mask, (float*)d_out);
}

// Round 2
// 593.294 us; speedup vs baseline: 1.0480x; 1.0480x over previous
//
#include <hip/hip_runtime.h>
#include <hip/hip_bf16.h>

// B=4, M=4096, N2=8192 (k/v split at 4096), D=HID=128, f32 in/out.
// out = rl * (e^(s*scale) @ V) + mask @ V   (fixed-max softmax, rl = 1/rowsum)
// ws (ushort): q[4][4096][128] | k[4][4096][128] | vT[4][128][4096] | Wq_bf | Wkv_bf

typedef __attribute__((ext_vector_type(8))) short bf16x8;
typedef __attribute__((ext_vector_type(4))) float f32x4;

static constexpr float kSc = 0.08838834764831845f * 1.4426950408889634f; // scale*log2e

__device__ __forceinline__ unsigned short f2bf(float f) {
  unsigned int u = __float_as_uint(f);
  u = (u + 0x7fffu + ((u >> 16) & 1u)) >> 16;   // RNE
  return (unsigned short)u;
}

__device__ __forceinline__ float fast_exp2(float v) {
#if __has_builtin(__builtin_amdgcn_exp2f)
  return __builtin_amdgcn_exp2f(v);
#else
  return exp2f(v);
#endif
}

// ---------------- kernel 0: W f32 -> bf16 (once) ----------------------------
__global__ __launch_bounds__(256) void wcvt_kernel(
    const float* __restrict__ Wq, const float* __restrict__ Wkv,
    unsigned short* __restrict__ wqb, unsigned short* __restrict__ wkb)
{
  const int t = blockIdx.x * 256 + threadIdx.x;   // 8 blocks -> 2048 threads, 8 elems each
  #pragma unroll
  for (int s = 0; s < 2; s++) {
    const float* src = s ? Wkv : Wq;
    unsigned short* dst = s ? wkb : wqb;
    float4 a = ((const float4*)src)[t * 2], b = ((const float4*)src)[t * 2 + 1];
    ushort4 o0 = make_ushort4(f2bf(a.x), f2bf(a.y), f2bf(a.z), f2bf(a.w));
    ushort4 o1 = make_ushort4(f2bf(b.x), f2bf(b.y), f2bf(b.z), f2bf(b.w));
    ((ushort4*)dst)[t * 2] = o0;
    ((ushort4*)dst)[t * 2 + 1] = o1;
  }
}

// ---------------- kernel 1: projections -------------------------------------
__global__ __launch_bounds__(256) void proj_kernel(
    const float* __restrict__ x, const float* __restrict__ cond,
    const unsigned short* __restrict__ wqb, const unsigned short* __restrict__ wkb,
    unsigned short* __restrict__ qws, unsigned short* __restrict__ kws,
    unsigned short* __restrict__ vTws)
{
  __shared__ __align__(16) unsigned short lds[128 * 88];   // 22.5KB, dual-purpose
  const int bid = blockIdx.x, tid = threadIdx.x;
  const int wave = tid >> 6, l = tid & 63, l15 = l & 15, l4 = l >> 4;

  const float* src; const unsigned short* W;
  int mode; size_t row0;
  if (bid < 256) { mode = 0; src = x; W = wqb; row0 = (size_t)bid * 64; }
  else { row0 = (size_t)(bid - 256) * 64; src = cond; W = wkb;
         mode = ((int)(row0 & 8191) < 4096) ? 1 : 2; }
  const size_t rw = row0 + wave * 16;

  // A rows (f32 -> bf16 in reg)
  f32x4 ar[8];
  const float* rp = src + (rw + l15) * 128 + l4 * 8;
  #pragma unroll
  for (int ks = 0; ks < 4; ks++) {
    ar[2 * ks]     = *(const f32x4*)(rp + ks * 32);
    ar[2 * ks + 1] = *(const f32x4*)(rp + ks * 32 + 4);
  }
  bf16x8 af[4];
  #pragma unroll
  for (int ks = 0; ks < 4; ks++) {
    bf16x8 a;
    #pragma unroll
    for (int j = 0; j < 4; j++) {
      a[j]     = (short)f2bf(ar[2 * ks][j]);
      a[4 + j] = (short)f2bf(ar[2 * ks + 1][j]);
    }
    af[ks] = a;
  }

  f32x4 acc[8];
  #pragma unroll
  for (int d = 0; d < 8; d++) acc[d] = (f32x4){0.f, 0.f, 0.f, 0.f};

  const unsigned short* wp = W + l15 * 128 + l4 * 8;
  #pragma unroll
  for (int d = 0; d < 8; d++)
    #pragma unroll
    for (int ks = 0; ks < 4; ks++) {
      bf16x8 wf = *(const bf16x8*)(wp + d * 16 * 128 + ks * 32);
      acc[d] = __builtin_amdgcn_mfma_f32_16x16x32_bf16(af[ks], wf, acc[d], 0, 0, 0);
    }

  if (mode < 2) {
    // LDS transpose tile [64][136] -> coalesced row stores
    #pragma unroll
    for (int d = 0; d < 8; d++)
      #pragma unroll
      for (int r = 0; r < 4; r++)
        lds[(wave * 16 + l4 * 4 + r) * 136 + d * 16 + l15] = f2bf(acc[d][r]);
    __syncthreads();
    size_t obase; unsigned short* outp;
    if (mode == 0) { outp = qws; obase = row0; }
    else { outp = kws; obase = (row0 >> 13) * 4096 + (row0 & 8191); }
    const int row = tid >> 2, ch = (tid & 3) * 32;
    const unsigned short* sp = lds + row * 136 + ch;
    unsigned short* gp = outp + (obase + row) * 128 + ch;
    #pragma unroll
    for (int i = 0; i < 4; i++)
      *(int4*)(gp + i * 8) = *(const int4*)(sp + i * 8);
  } else {
    // v rows: LDS transpose [128][88] -> vT[b][d][n]
    #pragma unroll
    for (int d = 0; d < 8; d++)
      #pragma unroll
      for (int r = 0; r < 4; r++)
        lds[(d * 16 + l15) * 88 + wave * 16 + l4 * 4 + r] = f2bf(acc[d][r]);
    __syncthreads();
    const size_t b = row0 >> 13;
    const int n0 = (int)(row0 & 8191) - 4096;
    const int dd = tid >> 1, half = tid & 1;
    const unsigned short* sp = lds + dd * 88 + half * 32;
    unsigned short* gp = vTws + ((size_t)b * 128 + dd) * 4096 + n0 + half * 32;
    #pragma unroll
    for (int i = 0; i < 4; i++)
      *(int4*)(gp + i * 8) = *(const int4*)(sp + i * 8);
  }
}

// ---------------- kernel 2: fused attention ---------------------------------
// 256 blocks x 512 thr (8 waves = 4 rowgrp x 2 n-half). Wave: 16 rows, 2048 n.
// Register-pipelined: K(nt+1), mask(nt+1) prefetch; mask direct-to-frag (no LDS).
__global__ __launch_bounds__(512, 2) void attn_kernel(
    const unsigned short* __restrict__ qws,
    const unsigned short* __restrict__ kws,
    const unsigned short* __restrict__ vTws,
    const float* __restrict__ mask,
    float* __restrict__ out)
{
  __shared__ __align__(16) unsigned short pbuf[8][16][72];  // P1 redistribution (wave-private)
  __shared__ __align__(16) float cb[64][128];               // cross-half combine
  __shared__ float stats[2][64];

  const int bid = blockIdx.x;
  const int xcd = bid & 7, grp = bid >> 3;
  const int b = xcd >> 1;                       // batch pinned to XCD pair
  const int m0 = (grp * 2 + (xcd & 1)) * 64;

  const int tid = threadIdx.x, w = tid >> 6, l = tid & 63;
  const int rg = w & 3, nh = w >> 2;
  const int l15 = l & 15, l4 = l >> 4;

  bf16x8 qf[4];
  {
    const unsigned short* qp = qws + ((size_t)b * 4096 + m0 + rg * 16 + l15) * 128 + l4 * 8;
    #pragma unroll
    for (int ks = 0; ks < 4; ks++) qf[ks] = *(const bf16x8*)(qp + ks * 32);
  }

  f32x4 acc1[8], acc2[8];
  #pragma unroll
  for (int d = 0; d < 8; d++) { acc1[d] = (f32x4){0,0,0,0}; acc2[d] = (f32x4){0,0,0,0}; }
  float lsum[4] = {0.f, 0.f, 0.f, 0.f};

  const unsigned short* kbase = kws  + (size_t)b * 4096 * 128 + (size_t)l15 * 128 + l4 * 8;
  const unsigned short* vbase = vTws + (size_t)b * 128 * 4096 + (size_t)l15 * 4096 + l4 * 8;
  const float* mbase = mask + ((size_t)b * 4096 + m0 + rg * 16 + l15) * 4096 + l4 * 8;

  const int nbase = nh * 2048;

  // prologue: prefetch K(0), mask(0)
  bf16x8 kf[4][4];
  #pragma unroll
  for (int ns = 0; ns < 4; ns++)
    #pragma unroll
    for (int ks = 0; ks < 4; ks++)
      kf[ns][ks] = *(const bf16x8*)(kbase + (size_t)(nbase + ns * 16) * 128 + ks * 32);
  f32x4 mreg[4];
  #pragma unroll
  for (int ks = 0; ks < 2; ks++)
    #pragma unroll
    for (int h = 0; h < 2; h++)
      mreg[ks * 2 + h] = *(const f32x4*)(mbase + nbase + ks * 32 + h * 4);

  for (int nt = 0; nt < 32; nt++) {
    const int n0 = nbase + nt * 64;
    const int nn = nbase + (nt < 31 ? nt + 1 : 31) * 64;   // clamped prefetch addr

    // V first half (d=0..3) issued before S
    bf16x8 vf[16];
    #pragma unroll
    for (int d = 0; d < 4; d++)
      #pragma unroll
      for (int ks = 0; ks < 2; ks++)
        vf[d * 2 + ks] = *(const bf16x8*)(vbase + (size_t)(d * 16) * 4096 + n0 + ks * 32);

    // S = q k^T from prefetched kf
    f32x4 sacc[4];
    #pragma unroll
    for (int ns = 0; ns < 4; ns++) {
      sacc[ns] = (f32x4){0,0,0,0};
      #pragma unroll
      for (int ks = 0; ks < 4; ks++)
        sacc[ns] = __builtin_amdgcn_mfma_f32_16x16x32_bf16(qf[ks], kf[ns][ks], sacc[ns], 0, 0, 0);
    }
    // refill K for next tile (covers full iteration of latency)
    #pragma unroll
    for (int ns = 0; ns < 4; ns++)
      #pragma unroll
      for (int ks = 0; ks < 4; ks++)
        kf[ns][ks] = *(const bf16x8*)(kbase + (size_t)(nn + ns * 16) * 128 + ks * 32);

    // mask frags from prefetched regs (no LDS), then refill
    bf16x8 a2[2];
    #pragma unroll
    for (int ks = 0; ks < 2; ks++) {
      bf16x8 t;
      #pragma unroll
      for (int j = 0; j < 4; j++) {
        t[j]     = (short)f2bf(mreg[ks * 2][j]);
        t[4 + j] = (short)f2bf(mreg[ks * 2 + 1][j]);
      }
      a2[ks] = t;
    }
    #pragma unroll
    for (int ks = 0; ks < 2; ks++)
      #pragma unroll
      for (int h = 0; h < 2; h++)
        mreg[ks * 2 + h] = *(const f32x4*)(mbase + nn + ks * 32 + h * 4);

    // P1 = e^t -> LDS (wave-private redistribution)
    #pragma unroll
    for (int ns = 0; ns < 4; ns++)
      #pragma unroll
      for (int r = 0; r < 4; r++) {
        float e = fast_exp2(sacc[ns][r] * kSc);
        lsum[r] += e;
        pbuf[w][l4 * 4 + r][ns * 16 + l15] = f2bf(e);
      }

    // V second half (d=4..7)
    #pragma unroll
    for (int d = 4; d < 8; d++)
      #pragma unroll
      for (int ks = 0; ks < 2; ks++)
        vf[d * 2 + ks] = *(const bf16x8*)(vbase + (size_t)(d * 16) * 4096 + n0 + ks * 32);

    bf16x8 a1[2];
    #pragma unroll
    for (int ks = 0; ks < 2; ks++)
      a1[ks] = *(const bf16x8*)&pbuf[w][l15][ks * 32 + l4 * 8];

    __builtin_amdgcn_s_setprio(1);
    // mask-PV first (independent of the exp/LDS chain)
    #pragma unroll
    for (int d = 0; d < 8; d++)
      #pragma unroll
      for (int ks = 0; ks < 2; ks++)
        acc2[d] = __builtin_amdgcn_mfma_f32_16x16x32_bf16(a2[ks], vf[d * 2 + ks], acc2[d], 0, 0, 0);
    #pragma unroll
    for (int d = 0; d < 8; d++)
      #pragma unroll
      for (int ks = 0; ks < 2; ks++)
        acc1[d] = __builtin_amdgcn_mfma_f32_16x16x32_bf16(a1[ks], vf[d * 2 + ks], acc1[d], 0, 0, 0);
    __builtin_amdgcn_s_setprio(0);
  }

  // row-sums: 16-lane reduce, combine halves via stats
  #pragma unroll
  for (int r = 0; r < 4; r++) {
    float s = lsum[r];
    s += __shfl_xor(s, 1); s += __shfl_xor(s, 2);
    s += __shfl_xor(s, 4); s += __shfl_xor(s, 8);
    lsum[r] = s;
  }
  if (l15 == 0)
    #pragma unroll
    for (int r = 0; r < 4; r++) stats[nh][rg * 16 + l4 * 4 + r] = lsum[r];
  __syncthreads();

  float rl[4];
  #pragma unroll
  for (int r = 0; r < 4; r++)
    rl[r] = 1.0f / (stats[0][rg * 16 + l4 * 4 + r] + stats[1][rg * 16 + l4 * 4 + r]);

  if (nh == 1)
    #pragma unroll
    for (int d = 0; d < 8; d++)
      #pragma unroll
      for (int r = 0; r < 4; r++)
        cb[rg * 16 + l4 * 4 + r][d * 16 + l15] = acc1[d][r] * rl[r] + acc2[d][r];
  __syncthreads();
  if (nh == 0) {
    float* op = out + ((size_t)b * 4096 + m0) * 128;
    #pragma unroll
    for (int d = 0; d < 8; d++)
      #pragma unroll
      for (int r = 0; r < 4; r++) {
        const int row = rg * 16 + l4 * 4 + r;
        op[(size_t)row * 128 + d * 16 + l15] =
            acc1[d][r] * rl[r] + acc2[d][r] + cb[row][d * 16 + l15];
      }
  }
}

extern "C" void kernel_launch(void* const* d_in, const int* in_sizes, int n_in,
                              void* d_out, int out_size, void* d_ws, size_t ws_size,
                              hipStream_t stream) {
  const float* x    = (const float*)d_in[0];
  const float* cond = (const float*)d_in[1];
  const float* mask = (const float*)d_in[2];
  const float* Wq   = (const float*)d_in[3];
  const float* Wkv  = (const float*)d_in[4];

  unsigned short* qws = (unsigned short*)d_ws;
  unsigned short* kws = qws + (size_t)4 * 4096 * 128;
  unsigned short* vT  = kws + (size_t)4 * 4096 * 128;
  unsigned short* wqb = vT  + (size_t)4 * 128 * 4096;
  unsigned short* wkb = wqb + 128 * 128;

  hipLaunchKernelGGL(wcvt_kernel, dim3(8), dim3(256), 0, stream, Wq, Wkv, wqb, wkb);
  hipLaunchKernelGGL(proj_kernel, dim3(768), dim3(256), 0, stream,
                     x, cond, wqb, wkb, qws, kws, vT);
  hipLaunchKernelGGL(attn_kernel, dim3(256), dim3(512), 0, stream,
                     qws, kws, vT, mask, (float*)d_out);
}